// Round 11
// baseline (76.737 us; speedup 1.0000x reference)
//
#include <hip/hip_runtime.h>
#include <math.h>

// NUFFT forward via separable phase + bf16 MFMA. No workspace.
// ksp[c,k] = sum_x Ex[k,x] * ( sum_y img[c,x,y] * Ey[k,y] )
// R11 = R7 (2 barriers per nt-iter — the ONLY structure that passes; all
// barrier-less variants R8-R10 fail, likely flat-op LDS stores tracked by
// vmcnt which only __syncthreads drains) + register double-buffer prefetch:
// tile nt+1's global loads are issued into the alternate reg set right after
// the first barrier and consumed a full iteration later, hiding L2 latency
// under cvt+write+MFMA+stageC. nt loop fully unrolled so buf[nt&1] is
// static (rule #20: runtime-indexed reg arrays spill to scratch).

#define K_TOTAL 8192
#define KB      32          // k's per block
#define NX      128
#define NY      128
#define EY_LD   136         // bf16 row stride (pad +8)
#define EX_LD   132         // f32 row stride (pad +4)

typedef short  bf16x8 __attribute__((ext_vector_type(8)));
typedef float  f32x4  __attribute__((ext_vector_type(4)));

__device__ inline unsigned short f32_to_bf16_rne(float f) {
    unsigned int u = __float_as_uint(f);
    u += 0x7FFFu + ((u >> 16) & 1u);
    return (unsigned short)(u >> 16);
}
__device__ inline unsigned pack2(float a, float b) {
    return (unsigned)f32_to_bf16_rne(a) | ((unsigned)f32_to_bf16_rne(b) << 16);
}

__global__ __launch_bounds__(512, 1) void nufft_mfma_kernel(
    const float* __restrict__ imgR,
    const float* __restrict__ imgI,
    const float* __restrict__ trj,
    float* __restrict__ out)
{
    __shared__ __align__(16) unsigned short eyR[KB][EY_LD];
    __shared__ __align__(16) unsigned short eyI[KB][EY_LD];
    __shared__ __align__(16) float exR[KB][EX_LD];
    __shared__ __align__(16) float exI[KB][EX_LD];
    // wave-private slabs: [coil][RI][16 rows * 128 y] bf16, swizzled in-row
    __shared__ __align__(16) unsigned short slab[8][2][16 * 128];

    const int tid = threadIdx.x;
    const int k0  = blockIdx.x * KB;

    // ---- Phase A: exponential tables (Ey bf16, Ex f32) ----
    for (int i = tid; i < KB * 128; i += 512) {
        const int kk = i >> 7;
        const int p  = i & 127;
        const float kx = trj[(k0 + kk) * 2 + 0];
        const float ky = trj[(k0 + kk) * 2 + 1];
        const float r  = (float)(p - 64) * (1.0f / 128.0f);

        float ty = -ky * r; ty -= floorf(ty);
        float sy, cy; __sincosf(6.283185307179586f * ty, &sy, &cy);
        eyR[kk][p] = f32_to_bf16_rne(cy);
        eyI[kk][p] = f32_to_bf16_rne(sy);

        float tx = -kx * r; tx -= floorf(tx);
        float sx, cx; __sincosf(6.283185307179586f * tx, &sx, &cx);
        exR[kk][p] = cx;
        exI[kk][p] = sx;
    }
    __syncthreads();

    const int wave  = tid >> 6;     // 0..7  == coil
    const int lane  = tid & 63;
    const int l15   = lane & 15;
    const int lg    = lane >> 4;    // 0..3
    const int c     = wave;
    const int rhalf = lane >> 5;    // which 8-row half this lane stages
    const int seg   = lane & 31;    // float4 segment within a row

    // ---- A-fragment preload: Ey, resident (R4-proven layout) ----
    // A layout (16x16x32): row = lane&15 (+16*kt), k slot = (lane>>4)*8 + idx.
    bf16x8 aR[2][4], aI[2][4];
#pragma unroll
    for (int kt = 0; kt < 2; ++kt)
#pragma unroll
        for (int ys = 0; ys < 4; ++ys) {
            const int row = kt * 16 + l15;
            const int y   = ys * 32 + lg * 8;
            aR[kt][ys] = *(const bf16x8*)&eyR[row][y];
            aI[kt][ys] = *(const bf16x8*)&eyI[row][y];
        }

    char* const myslabR = (char*)&slab[c][0][0];
    char* const myslabI = (char*)&slab[c][1][0];

    f32x4 outRe[2] = {{0,0,0,0},{0,0,0,0}};
    f32x4 outIm[2] = {{0,0,0,0},{0,0,0,0}};

    // ---- double-buffered staging registers ----
    float4 bufR[2][8], bufI[2][8];

    // prologue: tile 0 into buf[0] (coalesced: 32 lanes x 16B per row)
    {
        const float* pR = imgR + (c * NX + rhalf * 8) * NY + seg * 4;
        const float* pI = imgI + (c * NX + rhalf * 8) * NY + seg * 4;
#pragma unroll
        for (int j = 0; j < 8; ++j) {
            bufR[0][j] = *(const float4*)(pR + j * NY);
            bufI[0][j] = *(const float4*)(pI + j * NY);
        }
    }

    // ---- main loop: R7 barrier structure + alternate-reg prefetch ----
#pragma unroll
    for (int nt = 0; nt < 8; ++nt) {
        const int cur = nt & 1;
        const int nxt = cur ^ 1;
        const int x0  = nt * 16;

        __syncthreads();   // prev iteration's slab reads complete (all waves)

        // issue tile nt+1 loads into the ALTERNATE reg set; consumed next
        // iteration (after another full barrier) -> latency fully hidden
        if (nt < 7) {
            const float* pR = imgR + (c * NX + (nt + 1) * 16 + rhalf * 8) * NY + seg * 4;
            const float* pI = imgI + (c * NX + (nt + 1) * 16 + rhalf * 8) * NY + seg * 4;
#pragma unroll
            for (int j = 0; j < 8; ++j) {
                bufR[nxt][j] = *(const float4*)(pR + j * NY);
                bufI[nxt][j] = *(const float4*)(pI + j * NY);
            }
        }

        // cvt + swizzled ds_write of tile nt (consumes buf[cur])
#pragma unroll
        for (int j = 0; j < 8; ++j) {
            const int row = rhalf * 8 + j;
            const int off = row * 256 + ((seg * 8) ^ ((row & 15) << 4));
            uint2 pRv, pIv;
            pRv.x = pack2(bufR[cur][j].x, bufR[cur][j].y);
            pRv.y = pack2(bufR[cur][j].z, bufR[cur][j].w);
            pIv.x = pack2(bufI[cur][j].x, bufI[cur][j].y);
            pIv.y = pack2(bufI[cur][j].z, bufI[cur][j].w);
            *(uint2*)(myslabR + off) = pRv;
            *(uint2*)(myslabI + off) = pIv;
        }

        __syncthreads();   // slab writes visible (drains vmcnt+lgkmcnt)

        // ---- MFMA from private slab (R7-proven swizzle/layout) ----
        const int x = x0 + l15;
        f32x4 P[2] = {{0,0,0,0},{0,0,0,0}};
        f32x4 Q[2] = {{0,0,0,0},{0,0,0,0}};
        f32x4 U[2] = {{0,0,0,0},{0,0,0,0}};
        f32x4 V[2] = {{0,0,0,0},{0,0,0,0}};

        const int rowb = l15 * 256;
#pragma unroll
        for (int ys = 0; ys < 4; ++ys) {
            const int inb = (lg * 16 + ys * 64) ^ (l15 << 4);
            const bf16x8 bR = *(const bf16x8*)(myslabR + rowb + inb);
            const bf16x8 bI = *(const bf16x8*)(myslabI + rowb + inb);
#pragma unroll
            for (int kt = 0; kt < 2; ++kt) {
                P[kt] = __builtin_amdgcn_mfma_f32_16x16x32_bf16(aR[kt][ys], bR, P[kt], 0, 0, 0);
                Q[kt] = __builtin_amdgcn_mfma_f32_16x16x32_bf16(aI[kt][ys], bI, Q[kt], 0, 0, 0);
                U[kt] = __builtin_amdgcn_mfma_f32_16x16x32_bf16(aR[kt][ys], bI, U[kt], 0, 0, 0);
                V[kt] = __builtin_amdgcn_mfma_f32_16x16x32_bf16(aI[kt][ys], bR, V[kt], 0, 0, 0);
            }
        }

        // ---- Stage C: multiply by Ex[k,x], accumulate over this x-tile ----
        // C/D layout (m89-verified): col = lane&15 (x), row = (lane>>4)*4 + j (+16*kt)
#pragma unroll
        for (int kt = 0; kt < 2; ++kt) {
#pragma unroll
            for (int j = 0; j < 4; ++j) {
                const int kl = kt * 16 + lg * 4 + j;
                const float TR = P[kt][j] - Q[kt][j];
                const float TI = U[kt][j] + V[kt][j];
                const float eR = exR[kl][x];
                const float eI = exI[kl][x];
                outRe[kt][j] += eR * TR - eI * TI;
                outIm[kt][j] += eR * TI + eI * TR;
            }
        }
    }

    // ---- reduce over the 16 x-lanes; lanes with l15==0 write ----
#pragma unroll
    for (int kt = 0; kt < 2; ++kt) {
#pragma unroll
        for (int j = 0; j < 4; ++j) {
            float r_ = outRe[kt][j];
            float i_ = outIm[kt][j];
#pragma unroll
            for (int m = 1; m < 16; m <<= 1) {
                r_ += __shfl_xor(r_, m, 64);
                i_ += __shfl_xor(i_, m, 64);
            }
            if (l15 == 0) {
                const int kg = k0 + kt * 16 + lg * 4 + j;
                ((float2*)out)[c * K_TOTAL + kg] = make_float2(r_, i_);
            }
        }
    }
}

extern "C" void kernel_launch(void* const* d_in, const int* in_sizes, int n_in,
                              void* d_out, int out_size, void* d_ws, size_t ws_size,
                              hipStream_t stream) {
    const float* imgR = (const float*)d_in[0];
    const float* imgI = (const float*)d_in[1];
    const float* trj  = (const float*)d_in[2];
    float* out = (float*)d_out;

    hipLaunchKernelGGL(nufft_mfma_kernel, dim3(K_TOTAL / KB), dim3(512), 0, stream,
                       imgR, imgI, trj, out);
}

// Round 12
// 27.409 us; speedup vs baseline: 2.7998x; 2.7998x over previous
//
#include <hip/hip_runtime.h>
#include <math.h>

// NUFFT forward via separable phase + bf16 MFMA. No workspace.
// ksp[c,k] = sum_x Ex[k,x] * ( sum_y img[c,x,y] * Ey[k,y] )
// R12: R7 barrier discipline (the only structure that validates) with LDS
// double-buffered slab (NOT register double-buffer — R11 spilled: 70MB
// fetch / 119MB write of scratch). One barrier per nt-iter: prefetch
// loads -> MFMA from slab[cur] (hides L2 latency) -> cvt+write slab[cur^1]
// -> syncthreads. Ex tables dropped from LDS (computed on the fly from 8
// preloaded kx per lane) to fit 2x64KB slabs: LDS = 148.5 KB.

#define K_TOTAL 8192
#define KB      32          // k's per block
#define NX      128
#define NY      128
#define EY_LD   136         // bf16 row stride (pad +8)

typedef short  bf16x8 __attribute__((ext_vector_type(8)));
typedef float  f32x4  __attribute__((ext_vector_type(4)));

__device__ inline unsigned short f32_to_bf16_rne(float f) {
    unsigned int u = __float_as_uint(f);
    u += 0x7FFFu + ((u >> 16) & 1u);
    return (unsigned short)(u >> 16);
}
__device__ inline unsigned pack2(float a, float b) {
    return (unsigned)f32_to_bf16_rne(a) | ((unsigned)f32_to_bf16_rne(b) << 16);
}

__global__ __launch_bounds__(512, 2) void nufft_mfma_kernel(
    const float* __restrict__ imgR,
    const float* __restrict__ imgI,
    const float* __restrict__ trj,
    float* __restrict__ out)
{
    __shared__ __align__(16) unsigned short eyR[KB][EY_LD];
    __shared__ __align__(16) unsigned short eyI[KB][EY_LD];
    // double-buffered wave-private slabs: [buf][coil][RI][16 rows * 128 y]
    __shared__ __align__(16) unsigned short slab[2][8][2][16 * 128];

    const int tid = threadIdx.x;
    const int k0  = blockIdx.x * KB;

    // ---- Phase A: Ey table only (Ex is computed on the fly in stage C) ----
    for (int i = tid; i < KB * 128; i += 512) {
        const int kk = i >> 7;
        const int p  = i & 127;
        const float ky = trj[(k0 + kk) * 2 + 1];
        const float r  = (float)(p - 64) * (1.0f / 128.0f);
        float ty = -ky * r; ty -= floorf(ty);
        float sy, cy; __sincosf(6.283185307179586f * ty, &sy, &cy);
        eyR[kk][p] = f32_to_bf16_rne(cy);
        eyI[kk][p] = f32_to_bf16_rne(sy);
    }
    __syncthreads();

    const int wave  = tid >> 6;     // 0..7  == coil
    const int lane  = tid & 63;
    const int l15   = lane & 15;
    const int lg    = lane >> 4;    // 0..3
    const int c     = wave;
    const int rhalf = lane >> 5;    // which 8-row half this lane stages
    const int seg   = lane & 31;    // float4 segment within a row

    // kx preload: stage C needs kl = kt*16 + lg*4 + j (8 fixed k's per lane)
    float kxv[2][4];
#pragma unroll
    for (int kt = 0; kt < 2; ++kt)
#pragma unroll
        for (int j = 0; j < 4; ++j)
            kxv[kt][j] = trj[(k0 + kt * 16 + lg * 4 + j) * 2 + 0];

    // ---- A-fragment preload: Ey (R4-proven layout) ----
    // A layout (16x16x32): row = lane&15 (+16*kt), k slot = (lane>>4)*8 + idx.
    bf16x8 aR[2][4], aI[2][4];
#pragma unroll
    for (int kt = 0; kt < 2; ++kt)
#pragma unroll
        for (int ys = 0; ys < 4; ++ys) {
            const int row = kt * 16 + l15;
            const int y   = ys * 32 + lg * 8;
            aR[kt][ys] = *(const bf16x8*)&eyR[row][y];
            aI[kt][ys] = *(const bf16x8*)&eyI[row][y];
        }

    f32x4 outRe[2] = {{0,0,0,0},{0,0,0,0}};
    f32x4 outIm[2] = {{0,0,0,0},{0,0,0,0}};

    float4 bufR[8], bufI[8];   // single staging buffer (64 VGPR)

    // ---- prologue: tile 0 -> load, cvt, write slab[0] ----
    {
        const float* pR = imgR + (c * NX + rhalf * 8) * NY + seg * 4;
        const float* pI = imgI + (c * NX + rhalf * 8) * NY + seg * 4;
#pragma unroll
        for (int j = 0; j < 8; ++j) {
            bufR[j] = *(const float4*)(pR + j * NY);
            bufI[j] = *(const float4*)(pI + j * NY);
        }
        char* swR = (char*)&slab[0][c][0][0];
        char* swI = (char*)&slab[0][c][1][0];
#pragma unroll
        for (int j = 0; j < 8; ++j) {
            const int row = rhalf * 8 + j;
            const int off = row * 256 + ((seg * 8) ^ ((row & 15) << 4));
            uint2 pRv, pIv;
            pRv.x = pack2(bufR[j].x, bufR[j].y);
            pRv.y = pack2(bufR[j].z, bufR[j].w);
            pIv.x = pack2(bufI[j].x, bufI[j].y);
            pIv.y = pack2(bufI[j].z, bufI[j].w);
            *(uint2*)(swR + off) = pRv;
            *(uint2*)(swI + off) = pIv;
        }
    }
    __syncthreads();

    // ---- main loop: ONE barrier per iter; loads overlap MFMA+stageC ----
    for (int nt = 0; nt < 8; ++nt) {
        const int cur = nt & 1;
        const int x0  = nt * 16;

        // 1. prefetch tile nt+1 into buf (consumed after the MFMA section)
        if (nt < 7) {
            const float* pR = imgR + (c * NX + (nt + 1) * 16 + rhalf * 8) * NY + seg * 4;
            const float* pI = imgI + (c * NX + (nt + 1) * 16 + rhalf * 8) * NY + seg * 4;
#pragma unroll
            for (int j = 0; j < 8; ++j) {
                bufR[j] = *(const float4*)(pR + j * NY);
                bufI[j] = *(const float4*)(pI + j * NY);
            }
        }

        // 2. MFMA from slab[cur] (R7-proven swizzle/layout)
        const char* sbR = (const char*)&slab[cur][c][0][0];
        const char* sbI = (const char*)&slab[cur][c][1][0];
        f32x4 P[2] = {{0,0,0,0},{0,0,0,0}};
        f32x4 Q[2] = {{0,0,0,0},{0,0,0,0}};
        f32x4 U[2] = {{0,0,0,0},{0,0,0,0}};
        f32x4 V[2] = {{0,0,0,0},{0,0,0,0}};
        const int rowb = l15 * 256;
#pragma unroll
        for (int ys = 0; ys < 4; ++ys) {
            const int inb = (lg * 16 + ys * 64) ^ (l15 << 4);
            const bf16x8 bR = *(const bf16x8*)(sbR + rowb + inb);
            const bf16x8 bI = *(const bf16x8*)(sbI + rowb + inb);
#pragma unroll
            for (int kt = 0; kt < 2; ++kt) {
                P[kt] = __builtin_amdgcn_mfma_f32_16x16x32_bf16(aR[kt][ys], bR, P[kt], 0, 0, 0);
                Q[kt] = __builtin_amdgcn_mfma_f32_16x16x32_bf16(aI[kt][ys], bI, Q[kt], 0, 0, 0);
                U[kt] = __builtin_amdgcn_mfma_f32_16x16x32_bf16(aR[kt][ys], bI, U[kt], 0, 0, 0);
                V[kt] = __builtin_amdgcn_mfma_f32_16x16x32_bf16(aI[kt][ys], bR, V[kt], 0, 0, 0);
            }
        }

        // 3. stage C: Ex computed on the fly (same numerics as the table)
        const float rx = (float)(x0 + l15 - 64) * (1.0f / 128.0f);
#pragma unroll
        for (int kt = 0; kt < 2; ++kt) {
#pragma unroll
            for (int j = 0; j < 4; ++j) {
                float t = -kxv[kt][j] * rx; t -= floorf(t);
                float eI_, eR_; __sincosf(6.283185307179586f * t, &eI_, &eR_);
                const float TR = P[kt][j] - Q[kt][j];
                const float TI = U[kt][j] + V[kt][j];
                outRe[kt][j] += eR_ * TR - eI_ * TI;
                outIm[kt][j] += eR_ * TI + eI_ * TR;
            }
        }

        // 4. cvt + swizzled ds_write of tile nt+1 into slab[cur^1]
        if (nt < 7) {
            char* swR = (char*)&slab[cur ^ 1][c][0][0];
            char* swI = (char*)&slab[cur ^ 1][c][1][0];
#pragma unroll
            for (int j = 0; j < 8; ++j) {
                const int row = rhalf * 8 + j;
                const int off = row * 256 + ((seg * 8) ^ ((row & 15) << 4));
                uint2 pRv, pIv;
                pRv.x = pack2(bufR[j].x, bufR[j].y);
                pRv.y = pack2(bufR[j].z, bufR[j].w);
                pIv.x = pack2(bufI[j].x, bufI[j].y);
                pIv.y = pack2(bufI[j].z, bufI[j].w);
                *(uint2*)(swR + off) = pRv;
                *(uint2*)(swI + off) = pIv;
            }
        }

        __syncthreads();   // slab[cur^1] writes drained & visible for next iter
    }

    // ---- reduce over the 16 x-lanes; lanes with l15==0 write ----
#pragma unroll
    for (int kt = 0; kt < 2; ++kt) {
#pragma unroll
        for (int j = 0; j < 4; ++j) {
            float r_ = outRe[kt][j];
            float i_ = outIm[kt][j];
#pragma unroll
            for (int m = 1; m < 16; m <<= 1) {
                r_ += __shfl_xor(r_, m, 64);
                i_ += __shfl_xor(i_, m, 64);
            }
            if (l15 == 0) {
                const int kg = k0 + kt * 16 + lg * 4 + j;
                ((float2*)out)[c * K_TOTAL + kg] = make_float2(r_, i_);
            }
        }
    }
}

extern "C" void kernel_launch(void* const* d_in, const int* in_sizes, int n_in,
                              void* d_out, int out_size, void* d_ws, size_t ws_size,
                              hipStream_t stream) {
    const float* imgR = (const float*)d_in[0];
    const float* imgI = (const float*)d_in[1];
    const float* trj  = (const float*)d_in[2];
    float* out = (float*)d_out;

    hipLaunchKernelGGL(nufft_mfma_kernel, dim3(K_TOTAL / KB), dim3(512), 0, stream,
                       imgR, imgI, trj, out);
}

// Round 14
// 21.413 us; speedup vs baseline: 3.5836x; 1.2800x over previous
//
#include <hip/hip_runtime.h>
#include <math.h>

// NUFFT forward via separable phase + bf16 MFMA. No workspace.
// ksp[c,k] = sum_x Ex[k,x] * ( sum_y img[c,x,y] * Ey[k,y] )
// R14 = R13 k-split structure with PROVEN __sincosf numerics restored
// (bisection: R13's only never-validated element was __builtin_amdgcn_sin/
// cosf; everything structural audits clean). Block = 64 k's, 8 waves =
// (4 coils x 2 k-halves) sharing staged slabs -> per-block image traffic
// halved vs R12. LDS double-buffer, 1 barrier/iter, R7-proven swizzle.

#define K_TOTAL 8192
#define KB      64          // k's per block (2 halves of 32)
#define NX      128
#define NY      128
#define EY_LD   136         // bf16 row stride (pad +8)

typedef short  bf16x8 __attribute__((ext_vector_type(8)));
typedef float  f32x4  __attribute__((ext_vector_type(4)));

__device__ inline unsigned short f32_to_bf16_rne(float f) {
    unsigned int u = __float_as_uint(f);
    u += 0x7FFFu + ((u >> 16) & 1u);
    return (unsigned short)(u >> 16);
}
__device__ inline unsigned pack2(float a, float b) {
    return (unsigned)f32_to_bf16_rne(a) | ((unsigned)f32_to_bf16_rne(b) << 16);
}

__global__ __launch_bounds__(512, 2) void nufft_mfma_kernel(
    const float* __restrict__ imgR,
    const float* __restrict__ imgI,
    const float* __restrict__ trj,
    float* __restrict__ out)
{
    __shared__ __align__(16) unsigned short eyR[KB][EY_LD];
    __shared__ __align__(16) unsigned short eyI[KB][EY_LD];
    // double-buffered shared slabs: [buf][coil4][RI][16 rows * 128 y] bf16
    __shared__ __align__(16) unsigned short slab[2][4][2][16 * 128];

    const int tid = threadIdx.x;
    const int bid = blockIdx.x;
    const int cg  = bid >> 7;          // coil group: 0 -> coils 0..3, 1 -> 4..7
    const int kg0 = (bid & 127) * KB;  // base k of this block

    // ---- Phase A: Ey table, 64 rows (Ex on the fly in stage C) ----
    for (int i = tid; i < KB * 128; i += 512) {
        const int kk = i >> 7;
        const int p  = i & 127;
        const float ky = trj[(kg0 + kk) * 2 + 1];
        const float r  = (float)(p - 64) * (1.0f / 128.0f);
        float t = -ky * r; t -= floorf(t);           // revolutions in [0,1)
        float st, ct; __sincosf(6.283185307179586f * t, &st, &ct);
        eyR[kk][p] = f32_to_bf16_rne(ct);
        eyI[kk][p] = f32_to_bf16_rne(st);
    }
    __syncthreads();

    const int wave = tid >> 6;      // 0..7
    const int lane = tid & 63;
    const int l15  = lane & 15;
    const int lg   = lane >> 4;     // 0..3
    const int c4   = wave & 3;      // coil within group
    const int kh   = wave >> 2;     // k-half: 0 -> k 0..31, 1 -> k 32..63
    const int c    = cg * 4 + c4;   // global coil
    const int rr   = lane >> 3;     // 0..7: staging row within this wave's half
    const int sg   = lane & 7;      // 0..7: base float4 segment

    // kx preload for stage C: kl = kh*32 + kt*16 + lg*4 + j
    float kxv[2][4];
#pragma unroll
    for (int kt = 0; kt < 2; ++kt)
#pragma unroll
        for (int j = 0; j < 4; ++j)
            kxv[kt][j] = trj[(kg0 + kh * 32 + kt * 16 + lg * 4 + j) * 2 + 0];

    // ---- A-fragment preload: Ey rows kh*32 + kt*16 + l15 (R4-proven layout) ----
    bf16x8 aR[2][4], aI[2][4];
#pragma unroll
    for (int kt = 0; kt < 2; ++kt)
#pragma unroll
        for (int ys = 0; ys < 4; ++ys) {
            const int row = kh * 32 + kt * 16 + l15;
            const int y   = ys * 32 + lg * 8;
            aR[kt][ys] = *(const bf16x8*)&eyR[row][y];
            aI[kt][ys] = *(const bf16x8*)&eyI[row][y];
        }

    f32x4 outRe[2] = {{0,0,0,0},{0,0,0,0}};
    f32x4 outIm[2] = {{0,0,0,0},{0,0,0,0}};

    // staging: wave (c4,kh) stages rows kh*8+rr of coil c's tile.
    // lane loads 4 float4 per R/I: row (kh*8+rr), segs sg+8t.
    const int rl = kh * 8 + rr;     // row-local within the coil's 16-row tile
    float4 bufR[4], bufI[4];

    // ---- prologue: tile 0 -> load, cvt, write slab[0] ----
    {
        const float* pR = imgR + (c * NX + rl) * NY + sg * 4;
        const float* pI = imgI + (c * NX + rl) * NY + sg * 4;
#pragma unroll
        for (int t = 0; t < 4; ++t) {
            bufR[t] = *(const float4*)(pR + t * 32);
            bufI[t] = *(const float4*)(pI + t * 32);
        }
        char* swR = (char*)&slab[0][c4][0][0];
        char* swI = (char*)&slab[0][c4][1][0];
#pragma unroll
        for (int t = 0; t < 4; ++t) {
            const int s   = sg + 8 * t;
            const int off = rl * 256 + ((s * 8) ^ (rl << 4));
            uint2 pRv, pIv;
            pRv.x = pack2(bufR[t].x, bufR[t].y);
            pRv.y = pack2(bufR[t].z, bufR[t].w);
            pIv.x = pack2(bufI[t].x, bufI[t].y);
            pIv.y = pack2(bufI[t].z, bufI[t].w);
            *(uint2*)(swR + off) = pRv;
            *(uint2*)(swI + off) = pIv;
        }
    }
    __syncthreads();

    // ---- main loop: 1 barrier/iter; prefetch overlaps MFMA+stageC ----
    for (int nt = 0; nt < 8; ++nt) {
        const int cur = nt & 1;
        const int x0  = nt * 16;

        // 1. prefetch tile nt+1 into buf (consumed in step 4)
        if (nt < 7) {
            const float* pR = imgR + (c * NX + (nt + 1) * 16 + rl) * NY + sg * 4;
            const float* pI = imgI + (c * NX + (nt + 1) * 16 + rl) * NY + sg * 4;
#pragma unroll
            for (int t = 0; t < 4; ++t) {
                bufR[t] = *(const float4*)(pR + t * 32);
                bufI[t] = *(const float4*)(pI + t * 32);
            }
        }

        // 2. MFMA from slab[cur] (R7/R12-proven swizzle/layout)
        const char* sbR = (const char*)&slab[cur][c4][0][0];
        const char* sbI = (const char*)&slab[cur][c4][1][0];
        f32x4 P[2] = {{0,0,0,0},{0,0,0,0}};
        f32x4 Q[2] = {{0,0,0,0},{0,0,0,0}};
        f32x4 U[2] = {{0,0,0,0},{0,0,0,0}};
        f32x4 V[2] = {{0,0,0,0},{0,0,0,0}};
        const int rowb = l15 * 256;
#pragma unroll
        for (int ys = 0; ys < 4; ++ys) {
            const int inb = (lg * 16 + ys * 64) ^ (l15 << 4);
            const bf16x8 bR = *(const bf16x8*)(sbR + rowb + inb);
            const bf16x8 bI = *(const bf16x8*)(sbI + rowb + inb);
#pragma unroll
            for (int kt = 0; kt < 2; ++kt) {
                P[kt] = __builtin_amdgcn_mfma_f32_16x16x32_bf16(aR[kt][ys], bR, P[kt], 0, 0, 0);
                Q[kt] = __builtin_amdgcn_mfma_f32_16x16x32_bf16(aI[kt][ys], bI, Q[kt], 0, 0, 0);
                U[kt] = __builtin_amdgcn_mfma_f32_16x16x32_bf16(aR[kt][ys], bI, U[kt], 0, 0, 0);
                V[kt] = __builtin_amdgcn_mfma_f32_16x16x32_bf16(aI[kt][ys], bR, V[kt], 0, 0, 0);
            }
        }

        // 3. stage C: Ex on the fly (proven __sincosf numerics)
        const float rx = (float)(x0 + l15 - 64) * (1.0f / 128.0f);
#pragma unroll
        for (int kt = 0; kt < 2; ++kt) {
#pragma unroll
            for (int j = 0; j < 4; ++j) {
                float t = -kxv[kt][j] * rx; t -= floorf(t);
                float eI_, eR_; __sincosf(6.283185307179586f * t, &eI_, &eR_);
                const float TR = P[kt][j] - Q[kt][j];
                const float TI = U[kt][j] + V[kt][j];
                outRe[kt][j] += eR_ * TR - eI_ * TI;
                outIm[kt][j] += eR_ * TI + eI_ * TR;
            }
        }

        // 4. cvt + swizzled ds_write of tile nt+1 into slab[cur^1]
        if (nt < 7) {
            char* swR = (char*)&slab[cur ^ 1][c4][0][0];
            char* swI = (char*)&slab[cur ^ 1][c4][1][0];
#pragma unroll
            for (int t = 0; t < 4; ++t) {
                const int s   = sg + 8 * t;
                const int off = rl * 256 + ((s * 8) ^ (rl << 4));
                uint2 pRv, pIv;
                pRv.x = pack2(bufR[t].x, bufR[t].y);
                pRv.y = pack2(bufR[t].z, bufR[t].w);
                pIv.x = pack2(bufI[t].x, bufI[t].y);
                pIv.y = pack2(bufI[t].z, bufI[t].w);
                *(uint2*)(swR + off) = pRv;
                *(uint2*)(swI + off) = pIv;
            }
        }

        __syncthreads();   // slab[cur^1] visible to both k-half waves next iter
    }

    // ---- reduce over the 16 x-lanes; lanes with l15==0 write ----
#pragma unroll
    for (int kt = 0; kt < 2; ++kt) {
#pragma unroll
        for (int j = 0; j < 4; ++j) {
            float r_ = outRe[kt][j];
            float i_ = outIm[kt][j];
#pragma unroll
            for (int m = 1; m < 16; m <<= 1) {
                r_ += __shfl_xor(r_, m, 64);
                i_ += __shfl_xor(i_, m, 64);
            }
            if (l15 == 0) {
                const int kg = kg0 + kh * 32 + kt * 16 + lg * 4 + j;
                ((float2*)out)[c * K_TOTAL + kg] = make_float2(r_, i_);
            }
        }
    }
}

extern "C" void kernel_launch(void* const* d_in, const int* in_sizes, int n_in,
                              void* d_out, int out_size, void* d_ws, size_t ws_size,
                              hipStream_t stream) {
    const float* imgR = (const float*)d_in[0];
    const float* imgI = (const float*)d_in[1];
    const float* trj  = (const float*)d_in[2];
    float* out = (float*)d_out;

    hipLaunchKernelGGL(nufft_mfma_kernel, dim3(256), dim3(512), 0, stream,
                       imgR, imgI, trj, out);
}